// Round 22
// baseline (208.529 us; speedup 1.0000x reference)
//
#include <hip/hip_runtime.h>

#define NFEAT 512
#define NCLS  40
#define NPAD  48          // NCLS padded to 3 MFMA n-tiles of 16
#define DM 128            // padded bucket width (legacy direct path)

// partition parameters
#define NFB     512       // fine-bucket id space (256 nodes each); 391 used
#define P1B     512       // phase-1 block count
#define CH      2048      // edges per LDS sort chunk == region capacity
#define MSTR    513       // meta row stride (512 offsets + total)
#define BCAP3   12288     // LDS CSR capacity per 256-node bucket (mean 8192)

typedef __attribute__((ext_vector_type(8))) short bf16x8;   // 8 bf16 (4 VGPRs)
typedef __attribute__((ext_vector_type(4))) float f32x4;

__device__ __forceinline__ unsigned short f2bf(float f) {   // RNE f32->bf16
    unsigned int u = __builtin_bit_cast(unsigned int, f);
    return (unsigned short)((u + 0x7FFFu + ((u >> 16) & 1u)) >> 16);
}
__device__ __forceinline__ float bf2f(unsigned short h) {
    return __builtin_bit_cast(float, (unsigned int)h << 16);
}

__device__ __forceinline__ void load_edge(const void* adj, int int32_mode,
                                          int e, int E, int& r, int& c) {
    if (int32_mode) {
        const int* a = (const int*)adj;
        r = a[e]; c = a[(size_t)E + e];
    } else {
        const long long* a = (const long long*)adj;
        r = (int)a[e]; c = (int)a[(size_t)E + e];
    }
}

// wave-level inclusive scan (64 lanes, no barriers)
__device__ __forceinline__ int wave_iscan(int s, int lane) {
#pragma unroll
    for (int d = 1; d < 64; d <<= 1) {
        int v = __shfl_up(s, d);
        if (lane >= d) s += v;
    }
    return s;
}

// ---------------------------------------------------------------------------
// W [40][512] f32 -> Wb [48][512] bf16 (rows 40..47 zero); zero flag.
// ---------------------------------------------------------------------------
__global__ void wconv_kernel(const float* __restrict__ W,
                             unsigned short* __restrict__ Wb,
                             unsigned int* __restrict__ flag) {
    int i = blockIdx.x * blockDim.x + threadIdx.x;
    if (i == 0) *flag = 0u;
    if (i >= NPAD * NFEAT) return;
    int n = i >> 9;
    float v = (n < NCLS) ? W[i] : 0.0f;
    Wb[i] = f2bf(v);
}

// ===========================================================================
// FUSED (256 threads): blocks [0, P1B) = chunk-sort phase1 writing each
// sorted chunk CONTIGUOUSLY to its own region + a 513-int offset table
// (all writes coalesced; no SCAP/rank/overflow); blocks [P1B,...) = gemm.
// ===========================================================================
__global__ __launch_bounds__(256) void fused_p1_gemm(
        const float* __restrict__ x, const unsigned short* __restrict__ Wb,
        unsigned short* __restrict__ xwb, const void* __restrict__ adj,
        unsigned int* __restrict__ slices, int* __restrict__ meta,
        int N, int E, int NCHK) {
    __shared__ unsigned int   pbuf[CH];
    __shared__ unsigned short bbuf[CH];
    __shared__ unsigned int   sbuf[CH];
    __shared__ int hist[NFB], base[NFB], cur[NFB];
    __shared__ int wtot[4];
    __shared__ unsigned int det;

    const int t = threadIdx.x;
    const int lane = t & 63, wv = t >> 6;

    if (blockIdx.x < P1B) {
        const int blk = blockIdx.x;
        if (t == 0) det = 0u;
        __syncthreads();
        // inline dtype detect: odd 32-bit words all-zero <=> int64 storage
        const unsigned int* aw = (const unsigned int*)adj;
        unsigned int dv = aw[2 * t + 1] | aw[2 * (t + 256) + 1];
        if (dv) atomicOr(&det, 1u);
        __syncthreads();
        const int m32 = (det != 0);

        const int per_blk = (E + P1B - 1) / P1B;
        const int e0 = blk * per_blk;
        const int e1 = min(E, e0 + per_blk);

        for (int ck = 0; ck < NCHK; ++ck) {
            const int cb = e0 + ck * CH;
            const int n = min(CH, e1 - cb);
            int* mrow = meta + (size_t)(blk * NCHK + ck) * MSTR;
            if (n <= 0) {                       // empty region: zero meta
                for (int i = t; i < MSTR; i += 256) mrow[i] = 0;
                continue;
            }
            // 1. load + classify (coalesced)
            for (int i = t; i < CH; i += 256) {
                unsigned short b = 0xFFFFu; unsigned int p = 0;
                if (i < n) {
                    int r, c;
                    load_edge(adj, m32, cb + i, E, r, c);
                    if (r != c && (unsigned)r < (unsigned)N && (unsigned)c < (unsigned)N) {
                        b = (unsigned short)(c >> 8);
                        p = ((unsigned int)(c & 255) << 17) | (unsigned int)r;
                    }
                }
                bbuf[i] = b; pbuf[i] = p;
            }
            for (int i = t; i < NFB; i += 256) hist[i] = 0;
            __syncthreads();
            // 2. histogram
            for (int i = t; i < CH; i += 256) {
                unsigned short b = bbuf[i];
                if (b != 0xFFFFu) atomicAdd(&hist[b], 1);
            }
            __syncthreads();
            // 3. wave-scan over 512 bins; write offsets (coalesced meta)
            int h0 = hist[2 * t], h1 = hist[2 * t + 1];
            int s = h0 + h1;
            int inc = wave_iscan(s, lane);
            if (lane == 63) wtot[wv] = inc;
            __syncthreads();
            int pre = 0;
#pragma unroll
            for (int i = 0; i < 4; ++i) if (i < wv) pre += wtot[i];
            inc += pre;
            int excl = inc - s;
            base[2 * t] = excl;           cur[2 * t] = excl;
            base[2 * t + 1] = excl + h0;  cur[2 * t + 1] = excl + h0;
            mrow[2 * t] = excl;
            mrow[2 * t + 1] = excl + h0;
            if (t == 255) mrow[512] = excl + h0 + h1;   // nv
            __syncthreads();
            // 4. scatter into sorted LDS order (no rank/overflow logic)
            for (int i = t; i < CH; i += 256) {
                unsigned short b = bbuf[i];
                if (b != 0xFFFFu) {
                    int pos = atomicAdd(&cur[b], 1);
                    sbuf[pos] = pbuf[i];
                }
            }
            __syncthreads();
            // 5. CONTIGUOUS coalesced write-out of the sorted chunk
            const int nv = cur[NFB - 1];
            unsigned int* dst = slices + (size_t)(blk * NCHK + ck) * CH;
            for (int i = t; i < nv; i += 256) dst[i] = sbuf[i];
            __syncthreads();                    // protect sbuf reuse
        }
        return;
    }

    // ----- gemm role: xw = x @ W^T via mfma (verified) -----
    const int wid  = (int)(blockIdx.x - P1B) * 4 + wv;
    const int m0 = wid * 16;
    if (m0 >= N) return;
    const int frow = lane & 15, ks = lane >> 4;
    int grow = m0 + frow; if (grow > N - 1) grow = N - 1;
    const float* xr = x + (size_t)grow * NFEAT + ks * 8;
    const unsigned short* wb0 = Wb + (size_t)frow * NFEAT + ks * 8;
    const unsigned short* wb1 = wb0 + (size_t)16 * NFEAT;
    const unsigned short* wb2 = wb0 + (size_t)32 * NFEAT;

    f32x4 acc0 = {0.f, 0.f, 0.f, 0.f};
    f32x4 acc1 = {0.f, 0.f, 0.f, 0.f};
    f32x4 acc2 = {0.f, 0.f, 0.f, 0.f};

#pragma unroll
    for (int kk = 0; kk < NFEAT; kk += 32) {
        float4 xa = *reinterpret_cast<const float4*>(xr + kk);
        float4 xb = *reinterpret_cast<const float4*>(xr + kk + 4);
        bf16x8 a;
        a[0] = (short)f2bf(xa.x); a[1] = (short)f2bf(xa.y);
        a[2] = (short)f2bf(xa.z); a[3] = (short)f2bf(xa.w);
        a[4] = (short)f2bf(xb.x); a[5] = (short)f2bf(xb.y);
        a[6] = (short)f2bf(xb.z); a[7] = (short)f2bf(xb.w);
        bf16x8 b0 = *reinterpret_cast<const bf16x8*>(wb0 + kk);
        bf16x8 b1 = *reinterpret_cast<const bf16x8*>(wb1 + kk);
        bf16x8 b2 = *reinterpret_cast<const bf16x8*>(wb2 + kk);
        acc0 = __builtin_amdgcn_mfma_f32_16x16x32_bf16(a, b0, acc0, 0, 0, 0);
        acc1 = __builtin_amdgcn_mfma_f32_16x16x32_bf16(a, b1, acc1, 0, 0, 0);
        acc2 = __builtin_amdgcn_mfma_f32_16x16x32_bf16(a, b2, acc2, 0, 0, 0);
    }

    const int ccol = frow;
#pragma unroll
    for (int i = 0; i < 4; ++i) {
        int crow = m0 + ks * 4 + i;
        if (crow < N) {
            unsigned short* orow = xwb + (size_t)crow * NCLS;
            orow[ccol]      = f2bf(acc0[i]);
            orow[16 + ccol] = f2bf(acc1[i]);
            if (ccol < 8) orow[32 + ccol] = f2bf(acc2[i]);
        }
    }
}

// ---------------------------------------------------------------------------
// P2GATHER (1024 threads): one block per fine bucket. Collects the bucket's
// segments from all regions (L2-resident reads), builds LDS CSR, gathers.
// ---------------------------------------------------------------------------
__global__ __launch_bounds__(1024) void p2gather_kernel(
        const unsigned int* __restrict__ slices,
        const int* __restrict__ meta,
        const unsigned short* __restrict__ xwb,
        const float* __restrict__ bias,
        float* __restrict__ out, int N, int NPAIR) {
    __shared__ int hist[256], cur[256];
    __shared__ int nstart[256], ncnt[256];
    __shared__ int sbuf[BCAP3];               // 48 KB
    __shared__ int wtot[4];
    const int b = blockIdx.x, t = threadIdx.x;
    const int lane = t & 63, wv = t >> 6;

    if (t < 256) hist[t] = 0;
    __syncthreads();

    // pass 1: histogram over this bucket's segments in every region
    for (int p = t; p < NPAIR; p += 1024) {
        const int* mrow = meta + (size_t)p * MSTR;
        int s0 = mrow[b], s1 = mrow[b + 1];
        const unsigned int* reg = slices + (size_t)p * CH;
        for (int j = s0; j < s1; ++j)
            atomicAdd(&hist[reg[j] >> 17], 1);
    }
    __syncthreads();

    // wave-scan over 256 node bins (waves 0..3)
    int h = 0, inc = 0;
    if (t < 256) {
        h = hist[t];
        inc = wave_iscan(h, lane);
        if (lane == 63) wtot[wv] = inc;
    }
    __syncthreads();
    if (t < 256) {
        int pre = 0;
#pragma unroll
        for (int i = 0; i < 4; ++i) if (i < wv) pre += wtot[i];
        inc += pre;
        int excl = inc - h;
        cur[t] = excl;
        nstart[t] = excl;
        ncnt[t] = h;
    }
    __syncthreads();

    // pass 2: place r into LDS sorted-by-node order
    for (int p = t; p < NPAIR; p += 1024) {
        const int* mrow = meta + (size_t)p * MSTR;
        int s0 = mrow[b], s1 = mrow[b + 1];
        const unsigned int* reg = slices + (size_t)p * CH;
        for (int j = s0; j < s1; ++j) {
            unsigned int q = reg[j];
            int pos = atomicAdd(&cur[q >> 17], 1);
            if (pos < BCAP3) sbuf[pos] = (int)(q & 0x1FFFFu);
        }
    }
    __syncthreads();

    // ---- gather from LDS CSR (verified lane scheme) ----
    const int g = lane / 10, cl = lane % 10;   // lanes 60-63 idle
    const bool lact = (g < 6);
    for (int nl = wv; nl < 256; nl += 16) {
        int c = b * 256 + nl;
        if (c >= N) break;
        int st = nstart[nl];
        int d  = ncnt[nl];
        if (st + d > BCAP3) d = BCAP3 - st;    // safety clamp (never hit)
        float a0 = 0.f, a1 = 0.f, a2 = 0.f, a3 = 0.f;
        if (g == 0) {                          // self-loop row
            ushort4 v = *reinterpret_cast<const ushort4*>(
                xwb + (size_t)c * NCLS + cl * 4);
            a0 = bf2f(v.x); a1 = bf2f(v.y); a2 = bf2f(v.z); a3 = bf2f(v.w);
        }
        for (int e = 0; e < d; e += 12) {
            int i0 = e + g, i1 = e + 6 + g;
            if (lact && i0 < d) {
                int r = sbuf[st + i0];
                ushort4 v = *reinterpret_cast<const ushort4*>(
                    xwb + (size_t)r * NCLS + cl * 4);
                a0 += bf2f(v.x); a1 += bf2f(v.y); a2 += bf2f(v.z); a3 += bf2f(v.w);
            }
            if (lact && i1 < d) {
                int r = sbuf[st + i1];
                ushort4 v = *reinterpret_cast<const ushort4*>(
                    xwb + (size_t)r * NCLS + cl * 4);
                a0 += bf2f(v.x); a1 += bf2f(v.y); a2 += bf2f(v.z); a3 += bf2f(v.w);
            }
        }
        a0 += __shfl_down(a0, 30); a1 += __shfl_down(a1, 30);
        a2 += __shfl_down(a2, 30); a3 += __shfl_down(a3, 30);
        {
            float u0 = __shfl_down(a0, 10), v0 = __shfl_down(a0, 20);
            float u1 = __shfl_down(a1, 10), v1 = __shfl_down(a1, 20);
            float u2 = __shfl_down(a2, 10), v2 = __shfl_down(a2, 20);
            float u3 = __shfl_down(a3, 10), v3 = __shfl_down(a3, 20);
            a0 += u0 + v0; a1 += u1 + v1; a2 += u2 + v2; a3 += u3 + v3;
        }
        if (lane < 10) {
            float scale = 1.0f / (float)(d + 1);
            float4 bb = *reinterpret_cast<const float4*>(bias + cl * 4);
            float4 o;
            o.x = fmaf(scale, a0, bb.x);
            o.y = fmaf(scale, a1, bb.y);
            o.z = fmaf(scale, a2, bb.z);
            o.w = fmaf(scale, a3, bb.w);
            *reinterpret_cast<float4*>(out + (size_t)c * NCLS + cl * 4) = o;
        }
    }
}

// ===========================================================================
// LEGACY DIRECT PATH (fallback only)
// ===========================================================================
__global__ void detect_kernel(const unsigned int* __restrict__ w,
                              unsigned int* __restrict__ flag) {
    unsigned int v = 0;
    for (int i = 1 + 2 * (int)threadIdx.x; i < 65536; i += 2 * (int)blockDim.x)
        v |= w[i];
    if (v) atomicOr(flag, 1u);
}

__global__ __launch_bounds__(256) void gemm_kernel(
        const float* __restrict__ x, const unsigned short* __restrict__ Wb,
        unsigned short* __restrict__ xwb, int N) {
    const int wid  = (blockIdx.x * blockDim.x + threadIdx.x) >> 6;
    const int lane = threadIdx.x & 63;
    const int m0 = wid * 16;
    if (m0 >= N) return;
    const int frow = lane & 15, ks = lane >> 4;
    int grow = m0 + frow; if (grow > N - 1) grow = N - 1;
    const float* xr = x + (size_t)grow * NFEAT + ks * 8;
    const unsigned short* wb0 = Wb + (size_t)frow * NFEAT + ks * 8;
    const unsigned short* wb1 = wb0 + (size_t)16 * NFEAT;
    const unsigned short* wb2 = wb0 + (size_t)32 * NFEAT;

    f32x4 acc0 = {0.f, 0.f, 0.f, 0.f};
    f32x4 acc1 = {0.f, 0.f, 0.f, 0.f};
    f32x4 acc2 = {0.f, 0.f, 0.f, 0.f};

#pragma unroll
    for (int kk = 0; kk < NFEAT; kk += 32) {
        float4 xa = *reinterpret_cast<const float4*>(xr + kk);
        float4 xb = *reinterpret_cast<const float4*>(xr + kk + 4);
        bf16x8 a;
        a[0] = (short)f2bf(xa.x); a[1] = (short)f2bf(xa.y);
        a[2] = (short)f2bf(xa.z); a[3] = (short)f2bf(xa.w);
        a[4] = (short)f2bf(xb.x); a[5] = (short)f2bf(xb.y);
        a[6] = (short)f2bf(xb.z); a[7] = (short)f2bf(xb.w);
        bf16x8 b0 = *reinterpret_cast<const bf16x8*>(wb0 + kk);
        bf16x8 b1 = *reinterpret_cast<const bf16x8*>(wb1 + kk);
        bf16x8 b2 = *reinterpret_cast<const bf16x8*>(wb2 + kk);
        acc0 = __builtin_amdgcn_mfma_f32_16x16x32_bf16(a, b0, acc0, 0, 0, 0);
        acc1 = __builtin_amdgcn_mfma_f32_16x16x32_bf16(a, b1, acc1, 0, 0, 0);
        acc2 = __builtin_amdgcn_mfma_f32_16x16x32_bf16(a, b2, acc2, 0, 0, 0);
    }

    const int ccol = frow;
#pragma unroll
    for (int i = 0; i < 4; ++i) {
        int crow = m0 + ks * 4 + i;
        if (crow < N) {
            unsigned short* orow = xwb + (size_t)crow * NCLS;
            orow[ccol]      = f2bf(acc0[i]);
            orow[16 + ccol] = f2bf(acc1[i]);
            if (ccol < 8) orow[32 + ccol] = f2bf(acc2[i]);
        }
    }
}

__global__ void fused_bucket_kernel(const void* __restrict__ adj,
                                    const unsigned int* __restrict__ flag,
                                    int* __restrict__ cnt,
                                    int* __restrict__ src2, int E, int N) {
    int e = blockIdx.x * blockDim.x + threadIdx.x;
    if (e >= E) return;
    int r, c;
    load_edge(adj, *flag, e, E, r, c);
    if (r == c) return;
    if ((unsigned)r >= (unsigned)N || (unsigned)c >= (unsigned)N) return;
    int pos = atomicAdd(&cnt[c], 1);
    if (pos < DM) src2[(size_t)c * DM + pos] = r;
}

__global__ void gather_kernel(const unsigned short* __restrict__ xwb,
                              const int* __restrict__ deg,
                              const int* __restrict__ src,
                              const float* __restrict__ bias,
                              float* __restrict__ out, int N, int dm) {
    int wid = (blockIdx.x * blockDim.x + threadIdx.x) >> 6;
    int lane = threadIdx.x & 63;
    if (wid >= N) return;
    int start = wid * dm;
    int d = __builtin_amdgcn_readfirstlane(min(deg[wid], dm));

    const int g  = lane / 10;
    const int cl = lane % 10;
    const bool lact = (g < 6);
    float a0 = 0.f, a1 = 0.f, a2 = 0.f, a3 = 0.f;

    if (g == 0) {
        ushort4 v = *reinterpret_cast<const ushort4*>(
            xwb + (size_t)wid * NCLS + cl * 4);
        a0 = bf2f(v.x); a1 = bf2f(v.y); a2 = bf2f(v.z); a3 = bf2f(v.w);
    }

    const int* sp = src + start;
    for (int e = 0; e < d; e += 12) {
        int i0 = e + g, i1 = e + 6 + g;
        if (lact && i0 < d) {
            int r = sp[i0];
            ushort4 v = *reinterpret_cast<const ushort4*>(
                xwb + (size_t)r * NCLS + cl * 4);
            a0 += bf2f(v.x); a1 += bf2f(v.y); a2 += bf2f(v.z); a3 += bf2f(v.w);
        }
        if (lact && i1 < d) {
            int r = sp[i1];
            ushort4 v = *reinterpret_cast<const ushort4*>(
                xwb + (size_t)r * NCLS + cl * 4);
            a0 += bf2f(v.x); a1 += bf2f(v.y); a2 += bf2f(v.z); a3 += bf2f(v.w);
        }
    }

    a0 += __shfl_down(a0, 30); a1 += __shfl_down(a1, 30);
    a2 += __shfl_down(a2, 30); a3 += __shfl_down(a3, 30);
    {
        float u0 = __shfl_down(a0, 10), v0 = __shfl_down(a0, 20);
        float u1 = __shfl_down(a1, 10), v1 = __shfl_down(a1, 20);
        float u2 = __shfl_down(a2, 10), v2 = __shfl_down(a2, 20);
        float u3 = __shfl_down(a3, 10), v3 = __shfl_down(a3, 20);
        a0 += u0 + v0; a1 += u1 + v1; a2 += u2 + v2; a3 += u3 + v3;
    }

    if (lane < 10) {
        float scale = 1.0f / (float)(d + 1);
        float4 bb = *reinterpret_cast<const float4*>(bias + cl * 4);
        float4 o;
        o.x = fmaf(scale, a0, bb.x);
        o.y = fmaf(scale, a1, bb.y);
        o.z = fmaf(scale, a2, bb.z);
        o.w = fmaf(scale, a3, bb.w);
        *reinterpret_cast<float4*>(out + (size_t)wid * NCLS + cl * 4) = o;
    }
}

extern "C" void kernel_launch(void* const* d_in, const int* in_sizes, int n_in,
                              void* d_out, int out_size, void* d_ws, size_t ws_size,
                              hipStream_t stream) {
    const float* x   = (const float*)d_in[0];
    const void*  adj = d_in[1];
    const float* W   = (const float*)d_in[2];
    const float* b   = (const float*)d_in[3];
    float* out = (float*)d_out;

    const int N = in_sizes[0] / NFEAT;   // 100000
    const int E = in_sizes[1] / 2;       // 3200000
    const int NB = (N + 255) / 256;      // 391 fine buckets
    const int GEMMB = (N + 63) / 64;     // 4 waves x 16 rows per block
    const int per_blk = (E + P1B - 1) / P1B;
    const int NCHK = (per_blk + CH - 1) / CH;   // chunks (regions) per block
    const int NPAIR = P1B * NCHK;               // total regions

    char* ws = (char*)d_ws;
    size_t off = 0;
    auto alloc = [&](size_t bytes) { char* p = ws + off; off += (bytes + 15) & ~size_t(15); return p; };

    unsigned short* xwb = (unsigned short*)alloc((size_t)N * NCLS * 2);   // 8 MB
    int*   cnt          = (int*)  alloc((size_t)N * sizeof(int));
    unsigned int* flag  = (unsigned int*)alloc(16);
    unsigned short* Wb  = (unsigned short*)alloc((size_t)NPAD * NFEAT * 2);

    const size_t part_need = off
        + (((size_t)NPAIR * CH * 4 + 15) & ~size_t(15))             // slices ~17 MB
        + (((size_t)NPAIR * MSTR * 4 + 15) & ~size_t(15));          // meta ~4.2 MB
    const bool partition = (N <= NFB * 256) && (E >= 512) && (part_need <= ws_size);
    const size_t direct_need = off + (size_t)N * DM * sizeof(int);
    const bool direct = !partition && (direct_need <= ws_size);

    wconv_kernel<<<(NPAD * NFEAT + 255) / 256, 256, 0, stream>>>(W, Wb, flag);

    if (partition) {
        unsigned int* slices = (unsigned int*)alloc((size_t)NPAIR * CH * 4);
        int* meta = (int*)alloc((size_t)NPAIR * MSTR * 4);

        fused_p1_gemm<<<P1B + GEMMB, 256, 0, stream>>>(
            x, Wb, xwb, adj, slices, meta, N, E, NCHK);
        p2gather_kernel<<<NB, 1024, 0, stream>>>(slices, meta, xwb, b, out,
                                                 N, NPAIR);
    } else if (direct) {
        int* src2 = (int*)alloc((size_t)N * DM * sizeof(int));
        hipMemsetAsync(cnt, 0, (size_t)N * sizeof(int), stream);
        detect_kernel<<<1, 512, 0, stream>>>((const unsigned int*)adj, flag);
        gemm_kernel<<<GEMMB, 256, 0, stream>>>(x, Wb, xwb, N);
        fused_bucket_kernel<<<(E + 255) / 256, 256, 0, stream>>>(adj, flag, cnt, src2, E, N);
        gather_kernel<<<(N * 64 + 255) / 256, 256, 0, stream>>>(
            xwb, cnt, src2, b, out, N, DM);
    }
}

// Round 23
// 187.276 us; speedup vs baseline: 1.1135x; 1.1135x over previous
//
#include <hip/hip_runtime.h>

#define NFEAT 512
#define NCLS  40
#define NPAD  48          // NCLS padded to 3 MFMA n-tiles of 16
#define DM 128            // padded bucket width (legacy direct path)

// partition parameters (R17/R19/R20 proven config)
#define NFB     512       // fine-bucket id space (256 nodes each); 391 used
#define P1B     512       // phase-1 block count
#define CH      2048      // edges per LDS sort chunk
#define SCAP    64        // slice capacity per (bucket, block); mean ~12
#define BCAP3   12288     // LDS CSR capacity per 256-node bucket (mean 8192)
#define OVF_CAP 65536     // overflow ring (never populated in practice)

typedef __attribute__((ext_vector_type(8))) short bf16x8;   // 8 bf16 (4 VGPRs)
typedef __attribute__((ext_vector_type(4))) float f32x4;

__device__ __forceinline__ unsigned short f2bf(float f) {   // RNE f32->bf16
    unsigned int u = __builtin_bit_cast(unsigned int, f);
    return (unsigned short)((u + 0x7FFFu + ((u >> 16) & 1u)) >> 16);
}
__device__ __forceinline__ float bf2f(unsigned short h) {
    return __builtin_bit_cast(float, (unsigned int)h << 16);
}

__device__ __forceinline__ void load_edge(const void* adj, int int32_mode,
                                          int e, int E, int& r, int& c) {
    if (int32_mode) {
        const int* a = (const int*)adj;
        r = a[e]; c = a[(size_t)E + e];
    } else {
        const long long* a = (const long long*)adj;
        r = (int)a[e]; c = (int)a[(size_t)E + e];
    }
}

// wave-level inclusive scan (64 lanes, no barriers)
__device__ __forceinline__ int wave_iscan(int s, int lane) {
#pragma unroll
    for (int d = 1; d < 64; d <<= 1) {
        int v = __shfl_up(s, d);
        if (lane >= d) s += v;
    }
    return s;
}

// ---------------------------------------------------------------------------
// W [40][512] f32 -> Wb [48][512] bf16 (rows 40..47 zero); zero control vars.
// ---------------------------------------------------------------------------
__global__ void wconv_kernel(const float* __restrict__ W,
                             unsigned short* __restrict__ Wb,
                             unsigned int* __restrict__ flag,
                             int* __restrict__ ovf_cnt) {
    int i = blockIdx.x * blockDim.x + threadIdx.x;
    if (i == 0) { *flag = 0u; *ovf_cnt = 0; }
    if (i >= NPAD * NFEAT) return;
    int n = i >> 9;
    float v = (n < NCLS) ? W[i] : 0.0f;
    Wb[i] = f2bf(v);
}

// ===========================================================================
// FUSED (256 threads): blocks [0, P1B) = chunk-sort phase1 with WAVE-SCAN
// (scan barriers 16 -> 2 per chunk); blocks [P1B, ...) = MFMA gemm.
// ===========================================================================
__global__ __launch_bounds__(256) void fused_p1_gemm(
        const float* __restrict__ x, const unsigned short* __restrict__ Wb,
        unsigned short* __restrict__ xwb, const void* __restrict__ adj,
        unsigned int* __restrict__ slices, int* __restrict__ slice_cnt,
        unsigned long long* __restrict__ ovf, int* __restrict__ ovf_cnt,
        int N, int E) {
    __shared__ unsigned int   pbuf[CH];
    __shared__ unsigned short bbuf[CH];
    __shared__ unsigned int   sbuf[CH];
    __shared__ unsigned int   obuf[CH];
    __shared__ int hist[NFB], base[NFB], cur[NFB], gcur[NFB];
    __shared__ int wtot[4];
    __shared__ unsigned int det;

    const int t = threadIdx.x;
    const int lane = t & 63, wv = t >> 6;

    if (blockIdx.x < P1B) {
        // ----- phase 1: LDS chunk-sort into per-(bucket,block) slices -----
        const int blk = blockIdx.x;
        for (int i = t; i < NFB; i += 256) gcur[i] = 0;
        if (t == 0) det = 0u;
        __syncthreads();
        // inline dtype detect: odd 32-bit words all-zero <=> int64 storage
        const unsigned int* aw = (const unsigned int*)adj;
        unsigned int dv = aw[2 * t + 1] | aw[2 * (t + 256) + 1];
        if (dv) atomicOr(&det, 1u);
        __syncthreads();
        const int m32 = (det != 0);

        const int per_blk = (E + P1B - 1) / P1B;
        const int e0 = blk * per_blk;
        const int e1 = min(E, e0 + per_blk);

        for (int cb = e0; cb < e1; cb += CH) {
            const int n = min(CH, e1 - cb);
            // 1. load + classify (coalesced)
            for (int i = t; i < CH; i += 256) {
                unsigned short b = 0xFFFFu; unsigned int p = 0;
                if (i < n) {
                    int r, c;
                    load_edge(adj, m32, cb + i, E, r, c);
                    if (r != c && (unsigned)r < (unsigned)N && (unsigned)c < (unsigned)N) {
                        b = (unsigned short)(c >> 8);
                        p = ((unsigned int)(c & 255) << 17) | (unsigned int)r;
                    }
                }
                bbuf[i] = b; pbuf[i] = p;
            }
            for (int i = t; i < NFB; i += 256) hist[i] = 0;
            __syncthreads();
            // 2. histogram
            for (int i = t; i < CH; i += 256) {
                unsigned short b = bbuf[i];
                if (b != 0xFFFFu) atomicAdd(&hist[b], 1);
            }
            __syncthreads();
            // 3. WAVE-SCAN over 512 bins (thread owns 2; 6 shfl steps + 1 bar)
            int h0 = hist[2 * t], h1 = hist[2 * t + 1];
            int s = h0 + h1;
            int inc = wave_iscan(s, lane);
            if (lane == 63) wtot[wv] = inc;
            __syncthreads();
            int pre = 0;
#pragma unroll
            for (int i = 0; i < 4; ++i) if (i < wv) pre += wtot[i];
            inc += pre;
            int excl = inc - s;
            base[2 * t] = excl;           cur[2 * t] = excl;
            base[2 * t + 1] = excl + h0;  cur[2 * t + 1] = excl + h0;
            __syncthreads();
            // 4. scatter into sorted LDS order
            for (int i = t; i < CH; i += 256) {
                unsigned short b = bbuf[i];
                if (b != 0xFFFFu) {
                    unsigned int p = pbuf[i];
                    int pos = atomicAdd(&cur[b], 1);
                    int rank = gcur[b] + (pos - base[b]);
                    unsigned int tgt;
                    if (rank < SCAP) {
                        tgt = ((unsigned int)b * P1B + (unsigned int)blk) * SCAP + rank;
                    } else {
                        tgt = 0xFFFFFFFFu;
                        int oi = atomicAdd(ovf_cnt, 1);
                        if (oi < OVF_CAP)
                            ovf[oi] = ((unsigned long long)b << 32) | p;
                    }
                    sbuf[pos] = p;
                    obuf[pos] = tgt;
                }
            }
            __syncthreads();
            // 5. segment-coalesced write-out
            const int nv = cur[NFB - 1];
            for (int i = t; i < nv; i += 256) {
                unsigned int tgt = obuf[i];
                if (tgt != 0xFFFFFFFFu) slices[tgt] = sbuf[i];
            }
            // 6. advance persistent cursors
            gcur[2 * t]     += h0;
            gcur[2 * t + 1] += h1;
            __syncthreads();
        }

        for (int i = t; i < NFB; i += 256)
            slice_cnt[(size_t)i * P1B + blk] = min(gcur[i], SCAP);
        return;
    }

    // ----- gemm role: xw = x @ W^T via mfma (verified) -----
    const int wid  = (int)(blockIdx.x - P1B) * 4 + wv;
    const int m0 = wid * 16;
    if (m0 >= N) return;
    const int frow = lane & 15, ks = lane >> 4;
    int grow = m0 + frow; if (grow > N - 1) grow = N - 1;
    const float* xr = x + (size_t)grow * NFEAT + ks * 8;
    const unsigned short* wb0 = Wb + (size_t)frow * NFEAT + ks * 8;
    const unsigned short* wb1 = wb0 + (size_t)16 * NFEAT;
    const unsigned short* wb2 = wb0 + (size_t)32 * NFEAT;

    f32x4 acc0 = {0.f, 0.f, 0.f, 0.f};
    f32x4 acc1 = {0.f, 0.f, 0.f, 0.f};
    f32x4 acc2 = {0.f, 0.f, 0.f, 0.f};

#pragma unroll
    for (int kk = 0; kk < NFEAT; kk += 32) {
        float4 xa = *reinterpret_cast<const float4*>(xr + kk);
        float4 xb = *reinterpret_cast<const float4*>(xr + kk + 4);
        bf16x8 a;
        a[0] = (short)f2bf(xa.x); a[1] = (short)f2bf(xa.y);
        a[2] = (short)f2bf(xa.z); a[3] = (short)f2bf(xa.w);
        a[4] = (short)f2bf(xb.x); a[5] = (short)f2bf(xb.y);
        a[6] = (short)f2bf(xb.z); a[7] = (short)f2bf(xb.w);
        bf16x8 b0 = *reinterpret_cast<const bf16x8*>(wb0 + kk);
        bf16x8 b1 = *reinterpret_cast<const bf16x8*>(wb1 + kk);
        bf16x8 b2 = *reinterpret_cast<const bf16x8*>(wb2 + kk);
        acc0 = __builtin_amdgcn_mfma_f32_16x16x32_bf16(a, b0, acc0, 0, 0, 0);
        acc1 = __builtin_amdgcn_mfma_f32_16x16x32_bf16(a, b1, acc1, 0, 0, 0);
        acc2 = __builtin_amdgcn_mfma_f32_16x16x32_bf16(a, b2, acc2, 0, 0, 0);
    }

    const int ccol = frow;
#pragma unroll
    for (int i = 0; i < 4; ++i) {
        int crow = m0 + ks * 4 + i;
        if (crow < N) {
            unsigned short* orow = xwb + (size_t)crow * NCLS;
            orow[ccol]      = f2bf(acc0[i]);
            orow[16 + ccol] = f2bf(acc1[i]);
            if (ccol < 8) orow[32 + ccol] = f2bf(acc2[i]);
        }
    }
}

// ---------------------------------------------------------------------------
// P2GATHER (1024 threads): one block per fine bucket. Builds the bucket's
// CSR in LDS then gathers directly from LDS. Wave-scan for the 256-bin scan.
// ---------------------------------------------------------------------------
__global__ __launch_bounds__(1024) void p2gather_kernel(
        const unsigned int* __restrict__ slices,
        const int* __restrict__ slice_cnt,
        const unsigned long long* __restrict__ ovf,
        const int* __restrict__ ovf_cnt,
        const unsigned short* __restrict__ xwb,
        const float* __restrict__ bias,
        float* __restrict__ out, int N) {
    __shared__ int hist[256], cur[256];
    __shared__ int nstart[256], ncnt[256];
    __shared__ int scnt[P1B];                 // 2 KB
    __shared__ int sbuf[BCAP3];               // 48 KB
    __shared__ int wtot[4];
    const int b = blockIdx.x, t = threadIdx.x;
    const size_t sbase = (size_t)b * P1B * SCAP;
    const int lane = t & 63, wv = t >> 6;

    if (t < 256) hist[t] = 0;
    for (int i = t; i < P1B; i += 1024)
        scnt[i] = slice_cnt[(size_t)b * P1B + i];
    __syncthreads();

    // pass 1: histogram (coalesced predicated slice reads)
    for (int i = t; i < P1B * SCAP; i += 1024) {
        int s = i >> 6, k = i & 63;               // SCAP == 64
        if (k < scnt[s]) atomicAdd(&hist[slices[sbase + i] >> 17], 1);
    }
    const int no = min(*ovf_cnt, OVF_CAP);
    for (int i = t; i < no; i += 1024)
        if ((int)(ovf[i] >> 32) == b)
            atomicAdd(&hist[((unsigned int)ovf[i]) >> 17], 1);
    __syncthreads();

    // wave-scan over 256 node bins (waves 0..3)
    int h = 0, inc = 0;
    if (t < 256) {
        h = hist[t];
        inc = wave_iscan(h, lane);
        if (lane == 63) wtot[wv] = inc;
    }
    __syncthreads();
    if (t < 256) {
        int pre = 0;
#pragma unroll
        for (int i = 0; i < 4; ++i) if (i < wv) pre += wtot[i];
        inc += pre;
        int excl = inc - h;
        cur[t] = excl;
        nstart[t] = excl;
        ncnt[t] = h;
    }
    __syncthreads();

    // pass 2: scatter r into LDS sorted-by-node order
    for (int i = t; i < P1B * SCAP; i += 1024) {
        int s = i >> 6, k = i & 63;
        if (k < scnt[s]) {
            unsigned int p = slices[sbase + i];
            int pos = atomicAdd(&cur[p >> 17], 1);
            if (pos < BCAP3) sbuf[pos] = (int)(p & 0x1FFFFu);
        }
    }
    for (int i = t; i < no; i += 1024) {
        if ((int)(ovf[i] >> 32) == b) {
            unsigned int p = (unsigned int)ovf[i];
            int pos = atomicAdd(&cur[p >> 17], 1);
            if (pos < BCAP3) sbuf[pos] = (int)(p & 0x1FFFFu);
        }
    }
    __syncthreads();

    // ---- gather from LDS CSR (verified lane scheme) ----
    const int g = lane / 10, cl = lane % 10;   // lanes 60-63 idle
    const bool lact = (g < 6);
    for (int nl = wv; nl < 256; nl += 16) {
        int c = b * 256 + nl;
        if (c >= N) break;
        int st = nstart[nl];
        int d  = ncnt[nl];
        if (st + d > BCAP3) d = BCAP3 - st;    // safety clamp (never hit)
        float a0 = 0.f, a1 = 0.f, a2 = 0.f, a3 = 0.f;
        if (g == 0) {                          // self-loop row
            ushort4 v = *reinterpret_cast<const ushort4*>(
                xwb + (size_t)c * NCLS + cl * 4);
            a0 = bf2f(v.x); a1 = bf2f(v.y); a2 = bf2f(v.z); a3 = bf2f(v.w);
        }
        for (int e = 0; e < d; e += 12) {
            int i0 = e + g, i1 = e + 6 + g;
            if (lact && i0 < d) {
                int r = sbuf[st + i0];
                ushort4 v = *reinterpret_cast<const ushort4*>(
                    xwb + (size_t)r * NCLS + cl * 4);
                a0 += bf2f(v.x); a1 += bf2f(v.y); a2 += bf2f(v.z); a3 += bf2f(v.w);
            }
            if (lact && i1 < d) {
                int r = sbuf[st + i1];
                ushort4 v = *reinterpret_cast<const ushort4*>(
                    xwb + (size_t)r * NCLS + cl * 4);
                a0 += bf2f(v.x); a1 += bf2f(v.y); a2 += bf2f(v.z); a3 += bf2f(v.w);
            }
        }
        a0 += __shfl_down(a0, 30); a1 += __shfl_down(a1, 30);
        a2 += __shfl_down(a2, 30); a3 += __shfl_down(a3, 30);
        {
            float u0 = __shfl_down(a0, 10), v0 = __shfl_down(a0, 20);
            float u1 = __shfl_down(a1, 10), v1 = __shfl_down(a1, 20);
            float u2 = __shfl_down(a2, 10), v2 = __shfl_down(a2, 20);
            float u3 = __shfl_down(a3, 10), v3 = __shfl_down(a3, 20);
            a0 += u0 + v0; a1 += u1 + v1; a2 += u2 + v2; a3 += u3 + v3;
        }
        if (lane < 10) {
            float scale = 1.0f / (float)(d + 1);
            float4 bb = *reinterpret_cast<const float4*>(bias + cl * 4);
            float4 o;
            o.x = fmaf(scale, a0, bb.x);
            o.y = fmaf(scale, a1, bb.y);
            o.z = fmaf(scale, a2, bb.z);
            o.w = fmaf(scale, a3, bb.w);
            *reinterpret_cast<float4*>(out + (size_t)c * NCLS + cl * 4) = o;
        }
    }
}

// ===========================================================================
// LEGACY DIRECT PATH (fallback only)
// ===========================================================================
__global__ void detect_kernel(const unsigned int* __restrict__ w,
                              unsigned int* __restrict__ flag) {
    unsigned int v = 0;
    for (int i = 1 + 2 * (int)threadIdx.x; i < 65536; i += 2 * (int)blockDim.x)
        v |= w[i];
    if (v) atomicOr(flag, 1u);
}

__global__ __launch_bounds__(256) void gemm_kernel(
        const float* __restrict__ x, const unsigned short* __restrict__ Wb,
        unsigned short* __restrict__ xwb, int N) {
    const int wid  = (blockIdx.x * blockDim.x + threadIdx.x) >> 6;
    const int lane = threadIdx.x & 63;
    const int m0 = wid * 16;
    if (m0 >= N) return;
    const int frow = lane & 15, ks = lane >> 4;
    int grow = m0 + frow; if (grow > N - 1) grow = N - 1;
    const float* xr = x + (size_t)grow * NFEAT + ks * 8;
    const unsigned short* wb0 = Wb + (size_t)frow * NFEAT + ks * 8;
    const unsigned short* wb1 = wb0 + (size_t)16 * NFEAT;
    const unsigned short* wb2 = wb0 + (size_t)32 * NFEAT;

    f32x4 acc0 = {0.f, 0.f, 0.f, 0.f};
    f32x4 acc1 = {0.f, 0.f, 0.f, 0.f};
    f32x4 acc2 = {0.f, 0.f, 0.f, 0.f};

#pragma unroll
    for (int kk = 0; kk < NFEAT; kk += 32) {
        float4 xa = *reinterpret_cast<const float4*>(xr + kk);
        float4 xb = *reinterpret_cast<const float4*>(xr + kk + 4);
        bf16x8 a;
        a[0] = (short)f2bf(xa.x); a[1] = (short)f2bf(xa.y);
        a[2] = (short)f2bf(xa.z); a[3] = (short)f2bf(xa.w);
        a[4] = (short)f2bf(xb.x); a[5] = (short)f2bf(xb.y);
        a[6] = (short)f2bf(xb.z); a[7] = (short)f2bf(xb.w);
        bf16x8 b0 = *reinterpret_cast<const bf16x8*>(wb0 + kk);
        bf16x8 b1 = *reinterpret_cast<const bf16x8*>(wb1 + kk);
        bf16x8 b2 = *reinterpret_cast<const bf16x8*>(wb2 + kk);
        acc0 = __builtin_amdgcn_mfma_f32_16x16x32_bf16(a, b0, acc0, 0, 0, 0);
        acc1 = __builtin_amdgcn_mfma_f32_16x16x32_bf16(a, b1, acc1, 0, 0, 0);
        acc2 = __builtin_amdgcn_mfma_f32_16x16x32_bf16(a, b2, acc2, 0, 0, 0);
    }

    const int ccol = frow;
#pragma unroll
    for (int i = 0; i < 4; ++i) {
        int crow = m0 + ks * 4 + i;
        if (crow < N) {
            unsigned short* orow = xwb + (size_t)crow * NCLS;
            orow[ccol]      = f2bf(acc0[i]);
            orow[16 + ccol] = f2bf(acc1[i]);
            if (ccol < 8) orow[32 + ccol] = f2bf(acc2[i]);
        }
    }
}

__global__ void fused_bucket_kernel(const void* __restrict__ adj,
                                    const unsigned int* __restrict__ flag,
                                    int* __restrict__ cnt,
                                    int* __restrict__ src2, int E, int N) {
    int e = blockIdx.x * blockDim.x + threadIdx.x;
    if (e >= E) return;
    int r, c;
    load_edge(adj, *flag, e, E, r, c);
    if (r == c) return;
    if ((unsigned)r >= (unsigned)N || (unsigned)c >= (unsigned)N) return;
    int pos = atomicAdd(&cnt[c], 1);
    if (pos < DM) src2[(size_t)c * DM + pos] = r;
}

__global__ void gather_kernel(const unsigned short* __restrict__ xwb,
                              const int* __restrict__ deg,
                              const int* __restrict__ src,
                              const float* __restrict__ bias,
                              float* __restrict__ out, int N, int dm) {
    int wid = (blockIdx.x * blockDim.x + threadIdx.x) >> 6;
    int lane = threadIdx.x & 63;
    if (wid >= N) return;
    int start = wid * dm;
    int d = __builtin_amdgcn_readfirstlane(min(deg[wid], dm));

    const int g  = lane / 10;
    const int cl = lane % 10;
    const bool lact = (g < 6);
    float a0 = 0.f, a1 = 0.f, a2 = 0.f, a3 = 0.f;

    if (g == 0) {
        ushort4 v = *reinterpret_cast<const ushort4*>(
            xwb + (size_t)wid * NCLS + cl * 4);
        a0 = bf2f(v.x); a1 = bf2f(v.y); a2 = bf2f(v.z); a3 = bf2f(v.w);
    }

    const int* sp = src + start;
    for (int e = 0; e < d; e += 12) {
        int i0 = e + g, i1 = e + 6 + g;
        if (lact && i0 < d) {
            int r = sp[i0];
            ushort4 v = *reinterpret_cast<const ushort4*>(
                xwb + (size_t)r * NCLS + cl * 4);
            a0 += bf2f(v.x); a1 += bf2f(v.y); a2 += bf2f(v.z); a3 += bf2f(v.w);
        }
        if (lact && i1 < d) {
            int r = sp[i1];
            ushort4 v = *reinterpret_cast<const ushort4*>(
                xwb + (size_t)r * NCLS + cl * 4);
            a0 += bf2f(v.x); a1 += bf2f(v.y); a2 += bf2f(v.z); a3 += bf2f(v.w);
        }
    }

    a0 += __shfl_down(a0, 30); a1 += __shfl_down(a1, 30);
    a2 += __shfl_down(a2, 30); a3 += __shfl_down(a3, 30);
    {
        float u0 = __shfl_down(a0, 10), v0 = __shfl_down(a0, 20);
        float u1 = __shfl_down(a1, 10), v1 = __shfl_down(a1, 20);
        float u2 = __shfl_down(a2, 10), v2 = __shfl_down(a2, 20);
        float u3 = __shfl_down(a3, 10), v3 = __shfl_down(a3, 20);
        a0 += u0 + v0; a1 += u1 + v1; a2 += u2 + v2; a3 += u3 + v3;
    }

    if (lane < 10) {
        float scale = 1.0f / (float)(d + 1);
        float4 bb = *reinterpret_cast<const float4*>(bias + cl * 4);
        float4 o;
        o.x = fmaf(scale, a0, bb.x);
        o.y = fmaf(scale, a1, bb.y);
        o.z = fmaf(scale, a2, bb.z);
        o.w = fmaf(scale, a3, bb.w);
        *reinterpret_cast<float4*>(out + (size_t)wid * NCLS + cl * 4) = o;
    }
}

extern "C" void kernel_launch(void* const* d_in, const int* in_sizes, int n_in,
                              void* d_out, int out_size, void* d_ws, size_t ws_size,
                              hipStream_t stream) {
    const float* x   = (const float*)d_in[0];
    const void*  adj = d_in[1];
    const float* W   = (const float*)d_in[2];
    const float* b   = (const float*)d_in[3];
    float* out = (float*)d_out;

    const int N = in_sizes[0] / NFEAT;   // 100000
    const int E = in_sizes[1] / 2;       // 3200000
    const int NB = (N + 255) / 256;      // 391 fine buckets
    const int GEMMB = (N + 63) / 64;     // 4 waves x 16 rows per block

    char* ws = (char*)d_ws;
    size_t off = 0;
    auto alloc = [&](size_t bytes) { char* p = ws + off; off += (bytes + 15) & ~size_t(15); return p; };

    unsigned short* xwb = (unsigned short*)alloc((size_t)N * NCLS * 2);   // 8 MB
    int*   cnt          = (int*)  alloc((size_t)N * sizeof(int));
    unsigned int* flag  = (unsigned int*)alloc(16);
    int*   ovf_cnt      = (int*)  alloc(16);
    unsigned short* Wb  = (unsigned short*)alloc((size_t)NPAD * NFEAT * 2);

    const size_t part_need = off
        + (((size_t)NFB * P1B * SCAP * 4 + 15) & ~size_t(15))       // slices 67 MB
        + (((size_t)NFB * P1B * 4 + 15) & ~size_t(15))              // slice_cnt 1 MB
        + (size_t)OVF_CAP * 8;                                      // ovf ring
    const bool partition = (N <= NFB * 256) && (E >= 512) && (part_need <= ws_size);
    const size_t direct_need = off + (size_t)N * DM * sizeof(int);
    const bool direct = !partition && (direct_need <= ws_size);

    wconv_kernel<<<(NPAD * NFEAT + 255) / 256, 256, 0, stream>>>(W, Wb, flag, ovf_cnt);

    if (partition) {
        unsigned int* slices = (unsigned int*)alloc((size_t)NFB * P1B * SCAP * 4);
        int* slice_cnt = (int*)alloc((size_t)NFB * P1B * 4);
        unsigned long long* ovf = (unsigned long long*)alloc((size_t)OVF_CAP * 8);

        fused_p1_gemm<<<P1B + GEMMB, 256, 0, stream>>>(
            x, Wb, xwb, adj, slices, slice_cnt, ovf, ovf_cnt, N, E);
        p2gather_kernel<<<NB, 1024, 0, stream>>>(slices, slice_cnt, ovf, ovf_cnt,
                                                 xwb, b, out, N);
    } else if (direct) {
        int* src2 = (int*)alloc((size_t)N * DM * sizeof(int));
        hipMemsetAsync(cnt, 0, (size_t)N * sizeof(int), stream);
        detect_kernel<<<1, 512, 0, stream>>>((const unsigned int*)adj, flag);
        gemm_kernel<<<GEMMB, 256, 0, stream>>>(x, Wb, xwb, N);
        fused_bucket_kernel<<<(E + 255) / 256, 256, 0, stream>>>(adj, flag, cnt, src2, E, N);
        gather_kernel<<<(N * 64 + 255) / 256, 256, 0, stream>>>(
            xwb, cnt, src2, b, out, N, DM);
    }
}